// Round 8
// baseline (565.770 us; speedup 1.0000x reference)
//
#include <hip/hip_runtime.h>
#include <hip/hip_bf16.h>
#include <math.h>

// Problem constants (fixed by the reference setup_inputs)
#define BB 32
#define PP 24564
#define OO 16
#define CC 81
#define BP (BB * PP)

typedef unsigned long long ull;

__device__ __forceinline__ float sl1(float x) {
    float ax = fabsf(x);
    return ax < 1.0f ? 0.5f * ax * ax : ax - 0.5f;
}

// unaligned-by-16 (4B-aligned) float4 global load: conf row stride is 324 B
__device__ __forceinline__ float4 ld4u(const float* p) {
    float4 v;
    __builtin_memcpy(&v, p, 16);
    return v;
}

__device__ __forceinline__ float ald(const float* p) {
    return __hip_atomic_load(p, __ATOMIC_RELAXED, __HIP_MEMORY_SCOPE_AGENT);
}
__device__ __forceinline__ int aldi(const int* p) {
    return __hip_atomic_load(p, __ATOMIC_RELAXED, __HIP_MEMORY_SCOPE_AGENT);
}

// ---------------------------------------------------------------------------
// K1: one block per batch, 256 threads (NOT 1024 -- R6's 1024-thr variant
// squeezed VGPRs to 64 and spilled bpv/bpi to scratch: 593 us). Full prior
// scan (96 iters), registers only, wave butterfly + LDS reduce, PLAIN STORE
// of best_prior (no atomics -> no pre-zero -> memset dispatch deleted).
// Block 0 zeroes the 12 KB accumulator region (stream order covers k_ce2).
//   key = (iou_bits << 32) | (0xFFFFFFFF - p) -> max iou, tie: smallest p.
// ---------------------------------------------------------------------------
__global__ __launch_bounds__(256) void k_match(
        const float* __restrict__ priors, const float* __restrict__ truths,
        ull* __restrict__ best_prior /* [BB][OO] */,
        float* __restrict__ zero_base /* 3072 floats to clear */) {
    const int b = blockIdx.x;
    const int tid = threadIdx.x;
    __shared__ float tr[OO][4];
    __shared__ float tarea[OO];
    __shared__ ull red[4][OO];

    if (b == 0) {   // zero num_posS + acc + done_ctr + accS (12 KB)
        for (int i = tid; i < 3072; i += 256) zero_base[i] = 0.0f;
    }

    if (tid < OO * 4) ((float*)tr)[tid] = truths[b * OO * 4 + tid];
    __syncthreads();
    if (tid < OO) tarea[tid] = (tr[tid][2] - tr[tid][0]) * (tr[tid][3] - tr[tid][1]);
    __syncthreads();

    float bpv[OO];
    int bpi[OO];
#pragma unroll
    for (int o = 0; o < OO; o++) { bpv[o] = -1.0f; bpi[o] = -1; }

    for (int p = tid; p < PP; p += 256) {
        const float4 pr = ((const float4*)priors)[p];
        const float x1 = pr.x - pr.z * 0.5f, y1 = pr.y - pr.w * 0.5f;
        const float x2 = pr.x + pr.z * 0.5f, y2 = pr.y + pr.w * 0.5f;
        const float parea = (x2 - x1) * (y2 - y1);
#pragma unroll
        for (int o = 0; o < OO; o++) {
            const float lx = fmaxf(tr[o][0], x1), ly = fmaxf(tr[o][1], y1);
            const float rx = fminf(tr[o][2], x2), ry = fminf(tr[o][3], y2);
            const float iw = fmaxf(rx - lx, 0.0f), ih = fmaxf(ry - ly, 0.0f);
            const float inter = iw * ih;
            const float iou = inter / (tarea[o] + parea - inter);
            if (iou > bpv[o]) { bpv[o] = iou; bpi[o] = p; }    // p ascending
        }
    }

    const int wave = tid >> 6;
    const int lane = tid & 63;
#pragma unroll
    for (int o = 0; o < OO; o++) {
        ull key = (bpi[o] >= 0)
            ? (((ull)__float_as_uint(bpv[o]) << 32) |
               (ull)(0xFFFFFFFFu - (unsigned)bpi[o]))
            : 0ull;
#pragma unroll
        for (int d = 32; d; d >>= 1) {
            const ull other = __shfl_xor(key, d);
            key = (other > key) ? other : key;
        }
        if (lane == 0) red[wave][o] = key;
    }
    __syncthreads();
    if (tid < OO) {
        const ull k0 = red[0][tid], k1 = red[1][tid];
        const ull k2 = red[2][tid], k3 = red[3][tid];
        ull m = k0 > k1 ? k0 : k1;
        const ull m2 = k2 > k3 ? k2 : k3;
        m = m > m2 ? m : m2;
        best_prior[b * OO + tid] = m;        // plain store, no init needed
    }
}

// ---------------------------------------------------------------------------
// K2: one 64-row tile per block, NO LDS / NO barriers (proven R5/R7).
// 4 threads per row: direct-global float4 loads, in-register LSE with
// quartet shfl_xor; part==0 lane does match-recompute + epilogue; wave
// reduction + <=5 striped atomics per wave.
// ---------------------------------------------------------------------------
__global__ __launch_bounds__(256) void k_ce2(
        const float* __restrict__ conf, const float* __restrict__ obj,
        const float* __restrict__ loc, const float* __restrict__ priors,
        const float* __restrict__ truths, const int* __restrict__ labels,
        const ull* __restrict__ best_prior,
        float* __restrict__ mining /* [2][B][P]: [0]=obj [1]=c */,
        int* __restrict__ num_posS /* [8][BB] */,
        float* __restrict__ accS  /* [64][32] */) {
    const int tid = threadIdx.x;
    const int tile = blockIdx.x;                 // BP == 64 * gridDim.x
    const int row0 = tile * 64;
    const int r = tid >> 2;
    const int part = tid & 3;
    const int row = row0 + r;
    const float* rowp = conf + (size_t)row * CC;
    const int c0 = part * 20;

    const float4 v0 = ld4u(rowp + c0);
    const float4 v1 = ld4u(rowp + c0 + 4);
    const float4 v2 = ld4u(rowp + c0 + 8);
    const float4 v3 = ld4u(rowp + c0 + 12);
    const float4 v4 = ld4u(rowp + c0 + 16);
    const float ex = (part == 3) ? rowp[80] : 0.0f;

    float m = v0.x;
    m = fmaxf(m, v0.y); m = fmaxf(m, v0.z); m = fmaxf(m, v0.w);
    m = fmaxf(m, v1.x); m = fmaxf(m, v1.y); m = fmaxf(m, v1.z); m = fmaxf(m, v1.w);
    m = fmaxf(m, v2.x); m = fmaxf(m, v2.y); m = fmaxf(m, v2.z); m = fmaxf(m, v2.w);
    m = fmaxf(m, v3.x); m = fmaxf(m, v3.y); m = fmaxf(m, v3.z); m = fmaxf(m, v3.w);
    m = fmaxf(m, v4.x); m = fmaxf(m, v4.y); m = fmaxf(m, v4.z); m = fmaxf(m, v4.w);
    if (part == 3) m = fmaxf(m, ex);
    m = fmaxf(m, __shfl_xor(m, 1));
    m = fmaxf(m, __shfl_xor(m, 2));

    float s = 0.0f;
    s += __expf(v0.x - m); s += __expf(v0.y - m); s += __expf(v0.z - m); s += __expf(v0.w - m);
    s += __expf(v1.x - m); s += __expf(v1.y - m); s += __expf(v1.z - m); s += __expf(v1.w - m);
    s += __expf(v2.x - m); s += __expf(v2.y - m); s += __expf(v2.z - m); s += __expf(v2.w - m);
    s += __expf(v3.x - m); s += __expf(v3.y - m); s += __expf(v3.z - m); s += __expf(v3.w - m);
    s += __expf(v4.x - m); s += __expf(v4.y - m); s += __expf(v4.z - m); s += __expf(v4.w - m);
    if (part == 3) s += __expf(ex - m);
    s += __shfl_xor(s, 1);
    s += __shfl_xor(s, 2);
    const float lse = m + __logf(s);

    const int b = row / PP;
    bool pos = false;
    float my_l = 0.0f, my_co = 0.0f, my_cc = 0.0f;
    if (part == 0) {
        const int p = row - b * PP;
        const float4 pr = ((const float4*)priors)[p];
        const float x1 = pr.x - pr.z * 0.5f, y1 = pr.y - pr.w * 0.5f;
        const float x2 = pr.x + pr.z * 0.5f, y2 = pr.y + pr.w * 0.5f;
        const float parea = (x2 - x1) * (y2 - y1);
        float best = -1.0f;
        int ti = 0;
        const float4* trb = (const float4*)truths + b * OO;
#pragma unroll
        for (int o = 0; o < OO; o++) {
            const float4 t = trb[o];
            const float ta = (t.z - t.x) * (t.w - t.y);
            const float lx = fmaxf(t.x, x1), ly = fmaxf(t.y, y1);
            const float rx = fminf(t.z, x2), ry = fminf(t.w, y2);
            const float iw = fmaxf(rx - lx, 0.0f), ih = fmaxf(ry - ly, 0.0f);
            const float inter = iw * ih;
            const float iou = inter / (ta + parea - inter);
            if (iou > best) { best = iou; ti = o; }
        }
        float ov = best;
#pragma unroll
        for (int o = 0; o < OO; o++) {         // ascending o = last-writer-wins
            const unsigned fp = 0xFFFFFFFFu -
                (unsigned)(best_prior[b * OO + o] & 0xFFFFFFFFull);
            if (fp == (unsigned)p) { ti = o; ov = 2.0f; }
        }

        const int lbl = labels[b * OO + ti];
        const int tgt = (ov < 0.5f) ? 0 : lbl;
        const float ce_c = lse - rowp[tgt];

        const float2 o2 = ((const float2*)obj)[row];
        const float mo = fmaxf(o2.x, o2.y);
        const float lse_o = mo + __logf(__expf(o2.x - mo) + __expf(o2.y - mo));
        pos = tgt > 0;
        const float ce_o = lse_o - (pos ? o2.y : o2.x);

        mining[BP + row] = pos ? 0.0f : ce_c;   // mining_c
        mining[row]      = pos ? 0.0f : ce_o;   // mining_obj

        if (pos) {
            my_co = ce_o;
            my_cc = ce_c;
            const float4 t = trb[ti];
            const float gcx = ((t.x + t.z) * 0.5f - pr.x) / (0.1f * pr.z);
            const float gcy = ((t.y + t.w) * 0.5f - pr.y) / (0.1f * pr.w);
            const float gw = logf((t.z - t.x) / pr.z) / 0.2f;
            const float gh = logf((t.w - t.y) / pr.w) / 0.2f;
            const float4 ld = ((const float4*)loc)[row];
            my_l = sl1(ld.x - gcx) + sl1(ld.y - gcy) +
                   sl1(ld.z - gw) + sl1(ld.w - gh);
        }
    }

    const int lane = tid & 63;
    const int w = tid >> 6;
    const ull mpos = __ballot(pos);
    const int bw0 = __shfl(b, 0);
    const ull mb1 = __ballot(b != bw0);
#pragma unroll
    for (int d = 32; d; d >>= 1) {
        my_l  += __shfl_down(my_l,  d);
        my_co += __shfl_down(my_co, d);
        my_cc += __shfl_down(my_cc, d);
    }
    if (lane == 0 && mpos) {
        const int stripe = tile * 4 + w;
        const int cnt0 = __popcll(mpos & ~mb1);
        const int cnt1 = __popcll(mpos &  mb1);
        int* nps = num_posS + (stripe & 7) * BB;
        if (cnt0) atomicAdd(&nps[bw0], cnt0);
        if (cnt1) atomicAdd(&nps[bw0 + 1], cnt1);
        float* slot = accS + (size_t)(stripe & 63) * 32;
        atomicAdd(slot + 0, my_l);
        atomicAdd(slot + 1, my_co);
        atomicAdd(slot + 2, my_cc);
    }
}

// ---------------------------------------------------------------------------
// K3: top-k sums via 4-pass radix select. v8: REGISTER-RESIDENT -- each
// thread loads its 24-element slice ONCE into r[24]; all 4 histogram passes
// and the final threshold-sum run from registers (VALU + LDS only). ~70
// VGPR at launch_bounds(1024,1): no spill (512/wave available at 1 blk/CU).
// Per-wave privatized histograms. LAST-BLOCK FINALIZE via done-counter.
// ---------------------------------------------------------------------------
__global__ __launch_bounds__(1024, 1) void k_select_final(
        const float* __restrict__ mining /* [2][B][P] */,
        const int* __restrict__ num_posS /* [8][BB] */,
        float* __restrict__ acc /* [3]=neg_obj [4]=neg_c */,
        int* __restrict__ done_ctr,
        const float* __restrict__ accS /* [64][32] */,
        float* __restrict__ out) {
    const int arr = blockIdx.x >> 5;  // 0 = obj, 1 = c
    const int b = blockIdx.x & 31;
    const int tid = threadIdx.x;
    const int wv = tid >> 6;
    int np = 0;
#pragma unroll
    for (int s = 0; s < 8; s++) np += num_posS[s * BB + b];
    long long k64 = 3LL * np;
    const int k = (int)(k64 < (long long)(PP - 1) ? k64 : (long long)(PP - 1));

    __shared__ unsigned histw[16][256];   // 16 KiB, per-wave privatized
    __shared__ unsigned hist[256];
    __shared__ unsigned s_prefix;
    __shared__ int s_krem;
    __shared__ float wsum[16];
    __shared__ unsigned wcnt[16];
    __shared__ int s_last;

    if (k > 0) {
        const float* x = mining + ((size_t)arr * BB + b) * PP;
        // one memory scan: slice into registers (24 x 1024 >= PP)
        float rg[24];
#pragma unroll
        for (int j = 0; j < 23; j++) rg[j] = x[j * 1024 + tid];
        const bool v23 = tid < (PP - 23 * 1024);          // tid < 1012
        rg[23] = v23 ? x[23 * 1024 + tid] : 0.0f;

        if (tid == 0) { s_prefix = 0u; s_krem = k; }

        for (int shift = 24; shift >= 0; shift -= 8) {
            __syncthreads();
            for (int i = tid; i < 16 * 256; i += 1024) ((unsigned*)histw)[i] = 0u;
            const unsigned prefix = s_prefix;
            const unsigned pmask = (shift == 24) ? 0u : (0xFFFFFFFFu << (shift + 8));
            __syncthreads();
#pragma unroll
            for (int j = 0; j < 24; j++) {
                if (j < 23 || v23) {
                    const unsigned u = __float_as_uint(rg[j]);
                    if ((u & pmask) == prefix)
                        atomicAdd(&histw[wv][(u >> shift) & 255u], 1u);
                }
            }
            __syncthreads();
            if (tid < 256) {
                unsigned s = 0;
#pragma unroll
                for (int w = 0; w < 16; w++) s += histw[w][tid];
                hist[tid] = s;
            }
            __syncthreads();
            if (tid == 0) {
                const int krem = s_krem;
                unsigned cum = 0;
                int sel = 0;
                for (int byte = 255; byte >= 0; byte--) {
                    const unsigned h = hist[byte];
                    if (cum + h >= (unsigned)krem) { sel = byte; break; }
                    cum += h;
                }
                s_krem = krem - (int)cum;
                s_prefix = prefix | ((unsigned)sel << shift);
            }
        }
        __syncthreads();

        const unsigned t = s_prefix;
        float lsum = 0.0f;
        unsigned lcnt = 0;
#pragma unroll
        for (int j = 0; j < 24; j++) {
            if (j < 23 || v23) {
                if (__float_as_uint(rg[j]) > t) { lsum += rg[j]; lcnt++; }
            }
        }
#pragma unroll
        for (int d = 32; d; d >>= 1) {
            lsum += __shfl_down(lsum, d);
            lcnt += __shfl_down(lcnt, d);
        }
        if ((tid & 63) == 0) { wsum[wv] = lsum; wcnt[wv] = lcnt; }
        __syncthreads();
        if (tid == 0) {
            float ts = 0.0f;
            unsigned tc = 0;
#pragma unroll
            for (int w = 0; w < 16; w++) { ts += wsum[w]; tc += wcnt[w]; }
            const float tsum = ts + (float)(k - (int)tc) * __uint_as_float(t);
            atomicAdd(&acc[3 + arr], tsum);
        }
    }

    // ---- completion protocol: last block to arrive finalizes ----
    __syncthreads();
    __threadfence();                       // release: acc adds visible
    if (tid == 0) s_last = (atomicAdd(done_ctr, 1) == 63);
    __syncthreads();
    if (s_last) {
        __threadfence();                   // acquire side
        if (tid < 64) {
            float sl = ald(&accS[tid * 32 + 0]);
            float so = ald(&accS[tid * 32 + 1]);
            float sc = ald(&accS[tid * 32 + 2]);
            int np_b = 0, k_b = 0;
            if (tid < BB) {
#pragma unroll
                for (int s2 = 0; s2 < 8; s2++) np_b += aldi(&num_posS[s2 * BB + tid]);
                long long kk = 3LL * np_b;
                k_b = (int)(kk < (long long)(PP - 1) ? kk : (long long)(PP - 1));
            }
#pragma unroll
            for (int d = 32; d; d >>= 1) {
                sl += __shfl_down(sl, d);
                so += __shfl_down(so, d);
                sc += __shfl_down(sc, d);
                np_b += __shfl_down(np_b, d);
                k_b  += __shfl_down(k_b,  d);
            }
            if (tid == 0) {
                const float fN = (float)(np_b > 1 ? np_b : 1);
                const float fN1 = (float)(k_b > 1 ? k_b : 1);
                const float a3 = ald(&acc[3]);
                const float a4 = ald(&acc[4]);
                out[0] = sl / fN;
                out[1] = (sc + a4) / fN;
                out[2] = 0.4f * (so + a3) / fN1;
            }
        }
    }
}

extern "C" void kernel_launch(void* const* d_in, const int* in_sizes, int n_in,
                              void* d_out, int out_size, void* d_ws, size_t ws_size,
                              hipStream_t stream) {
    const float* loc_data  = (const float*)d_in[0];
    const float* conf_data = (const float*)d_in[1];
    const float* obj_data  = (const float*)d_in[2];
    const float* priors    = (const float*)d_in[3];
    const float* truths    = (const float*)d_in[4];
    const int*   labels    = (const int*)d_in[5];
    float* out = (float*)d_out;

    // Workspace layout (float offsets from ws_f):
    // [0, 2BP)              mining: [0]=obj, [1]=c
    // S = 2BP:
    // [S, S+1024)           best_prior: 512 ull (plain-stored, no init)
    // [S+1024, +256)        num_posS: 8 x 32 ints    } zeroed by k_match
    // [S+1280, +8)          acc ([3]=neg_obj [4]=neg_c) } block 0
    // [S+1288]              done_ctr (int)              } (3072 floats)
    // [S+2048, +2048)       accS: 64 stripes x 32 floats
    float* ws_f = (float*)d_ws;
    float* mining = ws_f;
    const size_t S = 2 * (size_t)BP;
    ull*   best_prior = (ull*)(ws_f + S);
    int*   num_posS   = (int*)(ws_f + S + 1024);
    float* acc        = ws_f + S + 1280;
    int*   done_ctr   = (int*)(ws_f + S + 1288);
    float* accS       = ws_f + S + 2048;
    float* zero_base  = ws_f + S + 1024;   // covers num_posS..accS (3072 f)

    k_match<<<BB, 256, 0, stream>>>(priors, truths, best_prior, zero_base);

    k_ce2<<<BP / 64, 256, 0, stream>>>(conf_data, obj_data, loc_data, priors,
                                       truths, labels, best_prior,
                                       mining, num_posS, accS);

    k_select_final<<<64, 1024, 0, stream>>>(mining, num_posS, acc, done_ctr,
                                            accS, out);
}